// Round 14
// baseline (341.580 us; speedup 1.0000x reference)
//
#include <hip/hip_runtime.h>

typedef int v4i __attribute__((ext_vector_type(4)));

// ---- d_out layout (floats) --------------------------------------------------
#define OFF_SYN   8388608ull
#define OFF_MEM   16777216ull
#define OFF_MEMH  33554432ull
#define AQ01_BYTE  50331648ull
#define AQ234_BYTE 134217728ull
#define A_BYTES    8388608ull
#define CNT_BYTES  2097152ull   // 4 gates x 4096 rows x 32 segs x u32

struct PrepArgs {
  const int4* src[5]; int4* dst[5];                 // pack part
  const float* W1[4]; const float* W2[4]; signed char* Wq;  // wdig part
};
struct GArgs {
  const signed char* ax[4];
  const signed char* ah;
  const signed char* Wq;
  const float* mem[4];
  const float* b1[4];
  const float* b2[4];
  const float* beta[4];
  const float* thr[4];
  float* out;
  unsigned int* cnt;
};
struct CArgs {
  const float* memo; const float* syn_prev; const float* mem_hidden;
  const float* thr[4]; const float* beta_h; const float* thr_h;
  float* hid; float* syn; float* memh;
  const unsigned int* cnt;
};

__device__ __forceinline__ void gload16(const void* gsrc, void* lds) {
  __builtin_amdgcn_global_load_lds(
      (__attribute__((address_space(1))) void*)(gsrc),
      (__attribute__((address_space(3))) void*)(lds), 16, 0, 0);
}

// ---- fused prep: spikes fp32->i8 (blocks 0..10239), W->3 digit planes (rest)
// Both parts are pure memory-bound streaming; merged to drop one launch tail.
__global__ __launch_bounds__(256) void k_prep(PrepArgs a) {
  if (blockIdx.x < 10240) {
    // ---- pack: spikes fp32 (0.0/1.0) -> int8 0/1 ----
    unsigned idx = blockIdx.x * 256u + threadIdx.x;   // 5 * 524288 threads
    unsigned arr = idx >> 19;
    unsigned off = idx & 524287u;
    const int4* s = a.src[arr] + (size_t)off * 4;
    int4 v0 = s[0], v1 = s[1], v2 = s[2], v3 = s[3];
    union { signed char c[16]; int4 v; } u;
    u.c[0]=(signed char)(v0.x!=0); u.c[1]=(signed char)(v0.y!=0);
    u.c[2]=(signed char)(v0.z!=0); u.c[3]=(signed char)(v0.w!=0);
    u.c[4]=(signed char)(v1.x!=0); u.c[5]=(signed char)(v1.y!=0);
    u.c[6]=(signed char)(v1.z!=0); u.c[7]=(signed char)(v1.w!=0);
    u.c[8]=(signed char)(v2.x!=0); u.c[9]=(signed char)(v2.y!=0);
    u.c[10]=(signed char)(v2.z!=0); u.c[11]=(signed char)(v2.w!=0);
    u.c[12]=(signed char)(v3.x!=0); u.c[13]=(signed char)(v3.y!=0);
    u.c[14]=(signed char)(v3.z!=0); u.c[15]=(signed char)(v3.w!=0);
    a.dst[arr][off] = u.v;
  } else {
    // ---- wdig: weights -> 3 balanced base-256 digit planes at scale 2^28 ----
    // w ~ U(-b,b), b = 1/sqrt(2048) -> |q| <= 5.94e6 fits 3 digits. (2 digits
    // cap scale at ~2^20 -> enc error ~8e-6 ~ np's own noise -> gate-spike
    // flips -> hidden absmax-1.0 coin flip. Keep 3-digit exact.) int32 path is
    // exact: pow2 scale has no fp32 rounding; lrintf=RNE; (q-r)>>8 exact.
    unsigned idx = (blockIdx.x - 10240u) * 256u + threadIdx.x;  // 4M threads
    unsigned g  = idx >> 20;
    unsigned n  = (idx >> 10) & 1023u;
    unsigned kk = (idx & 1023u) << 2;                 // k, multiple of 4
    const float* src = (kk < 2048u) ? (a.W1[g] + (size_t)n * 2048 + kk)
                                    : (a.W2[g] + (size_t)n * 2048 + (kk - 2048u));
    float4 w = *(const float4*)src;
    float wv[4] = {w.x, w.y, w.z, w.w};
    union { signed char c[4]; int i; } u0, u1, u2;
    #pragma unroll
    for (int e = 0; e < 4; ++e) {
      int q = (int)lrintf(wv[e] * 268435456.0f);      // 2^28, exact scale
      int r0 = ((q + 128) & 255) - 128; q = (q - r0) >> 8;
      int r1 = ((q + 128) & 255) - 128; q = (q - r1) >> 8;
      u0.c[e] = (signed char)r0; u1.c[e] = (signed char)r1; u2.c[e] = (signed char)q;
    }
    size_t gb = (size_t)g * 3ull * 1024ull * 4096ull;
    size_t base = (size_t)n * 4096 + kk;
    *(int*)(a.Wq + gb + 0ull * 4194304ull + base) = u0.i;
    *(int*)(a.Wq + gb + 1ull * 4194304ull + base) = u1.i;
    *(int*)(a.Wq + gb + 2ull * 4194304ull + base) = u2.i;
  }
}

// ---- exact i8 GEMM: per gate enc = [x|h] . W^T (3 digit planes) -------------
// R13 settled structure (best, 229us w/ fused count): BK=128, 2 LDS buffers
// 80KiB via gload_lds, ONE __syncthreads/step, 48-MFMA 16x16x64 cluster,
// setprio, sched_barrier fences, 2 blocks/CU. Round-14 single change: the 10
// stage-gloads issue IMMEDIATELY after the barrier (before the 20 frag
// ds_reads) - VMEM issue no longer queues behind DS issue, extending the
// gloads' window to the next vmcnt(0) by ~200-300cyc; their LDS-writes land
// after the read burst clears the DS pipe.
// Settled-by-measurement (do NOT revisit): counted-vmcnt (R6/R7/R8: 285-291),
// fine phases (R7), reg-staged A or B (R9/R10: 300-365), 32x32x32 MFMA
// (R11/R12: 264, structural 4-way conflict), (256,4) bounds (R2: acc spill).
__global__ __launch_bounds__(256, 2) void k_gemm(GArgs a) {
  __shared__ __align__(16) signed char As[2][128 * 128];
  __shared__ __align__(16) signed char Bs[2][3][64 * 128];
  const int tid = threadIdx.x;
  const int w = tid >> 6, l = tid & 63;
  const int wr = w >> 1, wc = w & 1;
  const int g = blockIdx.z, mt = blockIdx.y, nt = blockIdx.x;
  const int lr = l >> 3;   // 0..7  (staging row-within-segment)
  const int lk = l & 7;    // 0..7  (staging 16B chunk)

  v4i acc[3][4][2];
  v4i zero = {0, 0, 0, 0};
  #pragma unroll
  for (int d = 0; d < 3; ++d)
    #pragma unroll
    for (int mi = 0; mi < 4; ++mi)
      #pragma unroll
      for (int ni = 0; ni < 2; ++ni) acc[d][mi][ni] = zero;

  const signed char* Wg = a.Wq + (size_t)g * 3ull * 4194304ull
                               + (size_t)(nt * 64) * 4096ull;

  // stage K-tile [K0, K0+128) into buffer `buf` (10 gload16 per wave: 4 A+6 B)
  // LDS[r][c] holds global chunk c ^ (r&7): pre-swizzled source, linear dest.
  auto stage = [&](int buf, int K0) {
    const signed char* Ab; int kl;
    if (K0 < 2048) { Ab = a.ax[g]; kl = K0; } else { Ab = a.ah; kl = K0 - 2048; }
    #pragma unroll
    for (int c = 0; c < 4; ++c) {
      int s = w * 4 + c;          // segment 0..15 (8 rows each)
      int rl = s * 8 + lr;        // row 0..127
      gload16(Ab + (size_t)(mt * 128 + rl) * 2048 + kl + ((lk ^ (rl & 7)) << 4),
              &As[buf][s * 1024]);
    }
    #pragma unroll
    for (int c = 0; c < 6; ++c) {
      int idx = c * 4 + w;        // 0..23
      int d = idx >> 3, seg = idx & 7;
      int rl = seg * 8 + lr;      // row 0..63
      gload16(Wg + (size_t)d * 4194304ull + (size_t)rl * 4096ull + K0
                 + ((lk ^ (rl & 7)) << 4),
              &Bs[buf][d][seg * 1024]);
    }
  };

  stage(0, 0);
  int cur = 0;
  for (int t = 0; t < 32; ++t) {
    // vmcnt(0)+lgkmcnt(0)+s_barrier: waits the 10 gloads for buf[cur] (issued
    // a full 48-MFMA phase ago) and fences buf[cur^1] reads before overwrite.
    __syncthreads();

    // ---- prefetch next tile FIRST (max latency window to next barrier) ----
    if (t + 1 < 32) stage(cur ^ 1, (t + 1) * 128);

    // ---- then issue ALL frag reads (critical path) ----
    v4i av[2][4];
    v4i bv[2][3][2];
    #pragma unroll
    for (int h = 0; h < 2; ++h) {
      #pragma unroll
      for (int mi = 0; mi < 4; ++mi) {
        int ar = wr * 64 + mi * 16 + (l & 15);
        int cp = ((h << 2) + (l >> 4)) ^ (ar & 7);
        av[h][mi] = *(const v4i*)&As[cur][ar * 128 + cp * 16];
      }
      #pragma unroll
      for (int d = 0; d < 3; ++d)
        #pragma unroll
        for (int ni = 0; ni < 2; ++ni) {
          int br = wc * 32 + ni * 16 + (l & 15);
          int cp = ((h << 2) + (l >> 4)) ^ (br & 7);
          bv[h][d][ni] = *(const v4i*)&Bs[cur][d][br * 128 + cp * 16];
        }
    }
    // fence: no MFMA (or its lgkm wait) may hoist above; no read/stage sinks.
    __builtin_amdgcn_sched_barrier(0);

    __builtin_amdgcn_s_setprio(1);
    #pragma unroll
    for (int h = 0; h < 2; ++h)
      #pragma unroll
      for (int d = 0; d < 3; ++d)
        #pragma unroll
        for (int mi = 0; mi < 4; ++mi)
          #pragma unroll
          for (int ni = 0; ni < 2; ++ni)
            acc[d][mi][ni] = __builtin_amdgcn_mfma_i32_16x16x64_i8(
                av[h][mi], bv[h][d][ni], acc[d][mi][ni], 0, 0, 0);
    __builtin_amdgcn_s_setprio(0);
    // pin: keep all MFMAs (and their lgkm waits) above the next barrier so no
    // ds_read of buf[cur] can still be outstanding when it gets overwritten.
    __builtin_amdgcn_sched_barrier(0);
    cur ^= 1;
  }

  // epilogue: recombine digits exactly in f64, leaky step, write mem_new,
  // and (fused) count spikes per row over this wave's 32-col half.
  const float* b1 = a.b1[g];
  const float* b2 = a.b2[g];
  const float* memg = a.mem[g];
  float* outg = a.out + (size_t)g * 4194304ull;
  double beta = fmin(fmax((double)(*a.beta[g]), 0.0), 1.0);
  double thr = (double)(*a.thr[g]);
  const float thrf = *a.thr[g];
  #pragma unroll
  for (int mi = 0; mi < 4; ++mi) {
    unsigned long long msk[2][4];
    #pragma unroll
    for (int ni = 0; ni < 2; ++ni) {
      int m0 = mt * 128 + wr * 64 + mi * 16 + ((l >> 4) << 2);
      int n  = nt * 64 + wc * 32 + ni * 16 + (l & 15);
      double bsum = (double)b1[n] + (double)b2[n];
      #pragma unroll
      for (int j = 0; j < 4; ++j) {
        double e = (double)acc[2][mi][ni][j] * 65536.0
                 + (double)acc[1][mi][ni][j] * 256.0
                 + (double)acc[0][mi][ni][j];
        double enc = e * (1.0 / 268435456.0) + bsum;
        size_t o = (size_t)(m0 + j) * 1024 + n;
        double mp = (double)memg[o];
        double reset = (mp - thr > 0.0) ? 1.0 : 0.0;
        double mn = beta * mp + enc - reset * thr;
        float v = (float)mn;
        outg[o] = v;
        msk[ni][j] = __ballot(v > thrf);   // bit l: col l&15, row-grp l>>4
      }
    }
    // lane r<16 stores the count for frag-row r = grp*4 + j over 32 cols
    int r = l & 15, grp = r >> 2, j = r & 3;
    unsigned c = (unsigned)__popcll((msk[0][j] >> (grp * 16)) & 0xFFFFull)
               + (unsigned)__popcll((msk[1][j] >> (grp * 16)) & 0xFFFFull);
    if (l < 16)
      a.cnt[((size_t)g * 4096 + mt * 128 + wr * 64 + mi * 16 + r) * 32
            + nt * 2 + wc] = c;
  }
}

// ---- finalize: counts -> f,i,g,o -> syn, mem_h, hidden (all f64) ------------
template <bool USE_WS>
__global__ __launch_bounds__(256) void k_fin(CArgs a) {
  const int b = blockIdx.x, tid = threadIdx.x;
  const int w = tid >> 6, l = tid & 63;
  __shared__ int scnt[4];
  __shared__ double sval[3];
  if (USE_WS) {
    __shared__ int part[128];
    if (tid < 128)
      part[tid] = (int)a.cnt[((size_t)(tid >> 5) * 4096 + b) * 32 + (tid & 31)];
    __syncthreads();
    if (tid < 4) {
      int s = 0;
      #pragma unroll
      for (int i = 0; i < 32; ++i) s += part[tid * 32 + i];
      scnt[tid] = s;
    }
    __syncthreads();
  } else {
    const float* mg = a.memo + (size_t)w * 4194304ull + (size_t)b * 1024;
    const float thrw = *a.thr[w];
    int cnt = 0;
    #pragma unroll
    for (int p = 0; p < 16; ++p) {
      float v = mg[l + p * 64];
      cnt += ((v - thrw) > 0.0f) ? 1 : 0;
    }
    #pragma unroll
    for (int off = 32; off; off >>= 1) cnt += __shfl_down(cnt, off, 64);
    if (l == 0) scnt[w] = cnt;
    __syncthreads();
  }
  if (tid == 0) {
    double mf = scnt[0] * (1.0 / 1024.0);
    double mi = scnt[1] * (1.0 / 1024.0);
    double mgv = scnt[2] * (1.0 / 1024.0);
    double mo = scnt[3] * (1.0 / 1024.0);
    double f  = 1.0 / (1.0 + exp(-mf));
    double ii = 1.0 / (1.0 + exp(-mi));
    double gv = tanh(mgv);
    double oo = 1.0 / (1.0 + exp(-mo));
    sval[0] = f; sval[1] = ii * gv; sval[2] = oo;
  }
  __syncthreads();
  const double f = sval[0], ig = sval[1], oo = sval[2];
  const double bh = fmin(fmax((double)(*a.beta_h), 0.0), 1.0);
  const double th = (double)(*a.thr_h);
  const size_t rb = (size_t)b * 2048;
  for (int j = tid; j < 2048; j += 256) {
    double s = f * (double)a.syn_prev[rb + j] + ig;
    double mp = (double)a.mem_hidden[rb + j];
    double reset = (mp - th > 0.0) ? 1.0 : 0.0;
    double mh = bh * mp + oo * tanh(s) - reset * th;
    a.syn[rb + j] = (float)s;
    a.memh[rb + j] = (float)mh;
    a.hid[rb + j] = ((mh - th) > 0.0) ? 1.0f : 0.0f;
  }
}

extern "C" void kernel_launch(void* const* d_in, const int* in_sizes, int n_in,
                              void* d_out, int out_size, void* d_ws, size_t ws_size,
                              hipStream_t stream) {
  (void)in_sizes; (void)n_in; (void)out_size;
  float* out = (float*)d_out;
  signed char* base8 = (signed char*)d_out;
  const bool use_ws = (d_ws != nullptr) && (ws_size >= CNT_BYTES);

  PrepArgs pr;
  for (int i = 0; i < 5; ++i) {
    pr.src[i] = (const int4*)d_in[i];
    pr.dst[i] = (int4*)(base8 + (i < 2 ? (AQ01_BYTE + (size_t)i * A_BYTES)
                                       : (AQ234_BYTE + (size_t)(i - 2) * A_BYTES)));
  }
  pr.Wq = base8;
  for (int g = 0; g < 4; ++g) {
    pr.W1[g] = (const float*)d_in[11 + 4 * g];
    pr.W2[g] = (const float*)d_in[13 + 4 * g];
  }
  GArgs ga;
  for (int g = 0; g < 4; ++g) {
    ga.ax[g]   = (const signed char*)pr.dst[g];
    ga.mem[g]  = (const float*)d_in[6 + g];
    ga.b1[g]   = (const float*)d_in[12 + 4 * g];
    ga.b2[g]   = (const float*)d_in[14 + 4 * g];
    ga.beta[g] = (const float*)d_in[27 + 2 * g];
    ga.thr[g]  = (const float*)d_in[28 + 2 * g];
  }
  ga.ah = (const signed char*)pr.dst[4];
  ga.Wq = base8;
  ga.out = out + OFF_MEM;
  ga.cnt = (unsigned int*)d_ws;

  CArgs ca;
  ca.memo = out + OFF_MEM;
  ca.syn_prev = (const float*)d_in[5];
  ca.mem_hidden = (const float*)d_in[10];
  for (int g = 0; g < 4; ++g) ca.thr[g] = (const float*)d_in[28 + 2 * g];
  ca.beta_h = (const float*)d_in[35];
  ca.thr_h = (const float*)d_in[36];
  ca.hid = out;
  ca.syn = out + OFF_SYN;
  ca.memh = out + OFF_MEMH;
  ca.cnt = (const unsigned int*)d_ws;

  k_prep<<<26624, 256, 0, stream>>>(pr);
  k_gemm<<<dim3(16, 32, 4), 256, 0, stream>>>(ga);
  if (use_ws) k_fin<true><<<4096, 256, 0, stream>>>(ca);
  else        k_fin<false><<<4096, 256, 0, stream>>>(ca);
}

// Round 15
// 311.410 us; speedup vs baseline: 1.0969x; 1.0969x over previous
//
#include <hip/hip_runtime.h>

typedef int v4i __attribute__((ext_vector_type(4)));

// ---- d_out layout (floats) --------------------------------------------------
#define OFF_SYN   8388608ull
#define OFF_MEM   16777216ull
#define OFF_MEMH  33554432ull
#define AQ01_BYTE  50331648ull
#define AQ234_BYTE 134217728ull
#define A_BYTES    8388608ull
#define CNT_BYTES  2097152ull   // 4 gates x 4096 rows x 32 segs x u32

struct PrepArgs {
  const int4* src[5]; int4* dst[5];                 // pack part
  const float* W1[4]; const float* W2[4]; signed char* Wq;  // wdig part
};
struct GArgs {
  const signed char* ax[4];
  const signed char* ah;
  const signed char* Wq;
  const float* mem[4];
  const float* b1[4];
  const float* b2[4];
  const float* beta[4];
  const float* thr[4];
  float* out;
  unsigned int* cnt;
};
struct CArgs {
  const float* memo; const float* syn_prev; const float* mem_hidden;
  const float* thr[4]; const float* beta_h; const float* thr_h;
  float* hid; float* syn; float* memh;
  const unsigned int* cnt;
};

__device__ __forceinline__ void gload16(const void* gsrc, void* lds) {
  __builtin_amdgcn_global_load_lds(
      (__attribute__((address_space(1))) void*)(gsrc),
      (__attribute__((address_space(3))) void*)(lds), 16, 0, 0);
}

// ---- fused prep: spikes fp32->i8 (blocks 0..10239), W->3 digit planes (rest)
// Both parts are pure memory-bound streaming; merged to drop one launch tail
// (measured ~2us on the non-gemm portion, R14).
__global__ __launch_bounds__(256) void k_prep(PrepArgs a) {
  if (blockIdx.x < 10240) {
    // ---- pack: spikes fp32 (0.0/1.0) -> int8 0/1 ----
    unsigned idx = blockIdx.x * 256u + threadIdx.x;   // 5 * 524288 threads
    unsigned arr = idx >> 19;
    unsigned off = idx & 524287u;
    const int4* s = a.src[arr] + (size_t)off * 4;
    int4 v0 = s[0], v1 = s[1], v2 = s[2], v3 = s[3];
    union { signed char c[16]; int4 v; } u;
    u.c[0]=(signed char)(v0.x!=0); u.c[1]=(signed char)(v0.y!=0);
    u.c[2]=(signed char)(v0.z!=0); u.c[3]=(signed char)(v0.w!=0);
    u.c[4]=(signed char)(v1.x!=0); u.c[5]=(signed char)(v1.y!=0);
    u.c[6]=(signed char)(v1.z!=0); u.c[7]=(signed char)(v1.w!=0);
    u.c[8]=(signed char)(v2.x!=0); u.c[9]=(signed char)(v2.y!=0);
    u.c[10]=(signed char)(v2.z!=0); u.c[11]=(signed char)(v2.w!=0);
    u.c[12]=(signed char)(v3.x!=0); u.c[13]=(signed char)(v3.y!=0);
    u.c[14]=(signed char)(v3.z!=0); u.c[15]=(signed char)(v3.w!=0);
    a.dst[arr][off] = u.v;
  } else {
    // ---- wdig: weights -> 3 balanced base-256 digit planes at scale 2^28 ----
    // w ~ U(-b,b), b = 1/sqrt(2048) -> |q| <= 5.94e6 fits 3 digits. (2 digits
    // cap scale at ~2^20 -> enc error ~8e-6 ~ np's own noise -> gate-spike
    // flips -> hidden absmax-1.0 coin flip. Keep 3-digit exact.) int32 path is
    // exact: pow2 scale has no fp32 rounding; lrintf=RNE; (q-r)>>8 exact.
    unsigned idx = (blockIdx.x - 10240u) * 256u + threadIdx.x;  // 4M threads
    unsigned g  = idx >> 20;
    unsigned n  = (idx >> 10) & 1023u;
    unsigned kk = (idx & 1023u) << 2;                 // k, multiple of 4
    const float* src = (kk < 2048u) ? (a.W1[g] + (size_t)n * 2048 + kk)
                                    : (a.W2[g] + (size_t)n * 2048 + (kk - 2048u));
    float4 w = *(const float4*)src;
    float wv[4] = {w.x, w.y, w.z, w.w};
    union { signed char c[4]; int i; } u0, u1, u2;
    #pragma unroll
    for (int e = 0; e < 4; ++e) {
      int q = (int)lrintf(wv[e] * 268435456.0f);      // 2^28, exact scale
      int r0 = ((q + 128) & 255) - 128; q = (q - r0) >> 8;
      int r1 = ((q + 128) & 255) - 128; q = (q - r1) >> 8;
      u0.c[e] = (signed char)r0; u1.c[e] = (signed char)r1; u2.c[e] = (signed char)q;
    }
    size_t gb = (size_t)g * 3ull * 1024ull * 4096ull;
    size_t base = (size_t)n * 4096 + kk;
    *(int*)(a.Wq + gb + 0ull * 4194304ull + base) = u0.i;
    *(int*)(a.Wq + gb + 1ull * 4194304ull + base) = u1.i;
    *(int*)(a.Wq + gb + 2ull * 4194304ull + base) = u2.i;
  }
}

// ---- exact i8 GEMM: per gate enc = [x|h] . W^T (3 digit planes) -------------
// R13 settled structure VERBATIM (best, 229us w/ fused count): BK=128, 2 LDS
// buffers 80KiB via gload_lds, ONE __syncthreads/step, ALL 20 frag reads
// FIRST then the 10 stage-gloads (R14 A/B: stage-first = -31us regression —
// VMEM issue burst ahead of the critical-path ds_reads delays MFMA start),
// 48-MFMA 16x16x64 cluster, setprio, sched_barrier fences, 2 blocks/CU.
// Settled-by-measurement (do NOT revisit): counted-vmcnt (R6/R7/R8: 285-291),
// fine phases (R7), reg-staged A or B (R9/R10: 300-365), 32x32x32 MFMA
// (R11/R12: 264, structural 4-way conflict), (256,4) bounds (R2: acc spill),
// stage-before-reads (R14: 260).
__global__ __launch_bounds__(256, 2) void k_gemm(GArgs a) {
  __shared__ __align__(16) signed char As[2][128 * 128];
  __shared__ __align__(16) signed char Bs[2][3][64 * 128];
  const int tid = threadIdx.x;
  const int w = tid >> 6, l = tid & 63;
  const int wr = w >> 1, wc = w & 1;
  const int g = blockIdx.z, mt = blockIdx.y, nt = blockIdx.x;
  const int lr = l >> 3;   // 0..7  (staging row-within-segment)
  const int lk = l & 7;    // 0..7  (staging 16B chunk)

  v4i acc[3][4][2];
  v4i zero = {0, 0, 0, 0};
  #pragma unroll
  for (int d = 0; d < 3; ++d)
    #pragma unroll
    for (int mi = 0; mi < 4; ++mi)
      #pragma unroll
      for (int ni = 0; ni < 2; ++ni) acc[d][mi][ni] = zero;

  const signed char* Wg = a.Wq + (size_t)g * 3ull * 4194304ull
                               + (size_t)(nt * 64) * 4096ull;

  // stage K-tile [K0, K0+128) into buffer `buf` (10 gload16 per wave: 4 A+6 B)
  // LDS[r][c] holds global chunk c ^ (r&7): pre-swizzled source, linear dest.
  auto stage = [&](int buf, int K0) {
    const signed char* Ab; int kl;
    if (K0 < 2048) { Ab = a.ax[g]; kl = K0; } else { Ab = a.ah; kl = K0 - 2048; }
    #pragma unroll
    for (int c = 0; c < 4; ++c) {
      int s = w * 4 + c;          // segment 0..15 (8 rows each)
      int rl = s * 8 + lr;        // row 0..127
      gload16(Ab + (size_t)(mt * 128 + rl) * 2048 + kl + ((lk ^ (rl & 7)) << 4),
              &As[buf][s * 1024]);
    }
    #pragma unroll
    for (int c = 0; c < 6; ++c) {
      int idx = c * 4 + w;        // 0..23
      int d = idx >> 3, seg = idx & 7;
      int rl = seg * 8 + lr;      // row 0..63
      gload16(Wg + (size_t)d * 4194304ull + (size_t)rl * 4096ull + K0
                 + ((lk ^ (rl & 7)) << 4),
              &Bs[buf][d][seg * 1024]);
    }
  };

  stage(0, 0);
  int cur = 0;
  for (int t = 0; t < 32; ++t) {
    // vmcnt(0)+lgkmcnt(0)+s_barrier: waits the 10 gloads for buf[cur] (issued
    // a full 48-MFMA phase ago) and fences buf[cur^1] reads before overwrite.
    __syncthreads();

    // ---- issue ALL frag reads first (critical path) ----
    v4i av[2][4];
    v4i bv[2][3][2];
    #pragma unroll
    for (int h = 0; h < 2; ++h) {
      #pragma unroll
      for (int mi = 0; mi < 4; ++mi) {
        int ar = wr * 64 + mi * 16 + (l & 15);
        int cp = ((h << 2) + (l >> 4)) ^ (ar & 7);
        av[h][mi] = *(const v4i*)&As[cur][ar * 128 + cp * 16];
      }
      #pragma unroll
      for (int d = 0; d < 3; ++d)
        #pragma unroll
        for (int ni = 0; ni < 2; ++ni) {
          int br = wc * 32 + ni * 16 + (l & 15);
          int cp = ((h << 2) + (l >> 4)) ^ (br & 7);
          bv[h][d][ni] = *(const v4i*)&Bs[cur][d][br * 128 + cp * 16];
        }
    }
    // ---- then prefetch next tile (has a full interval to complete) ----
    if (t + 1 < 32) stage(cur ^ 1, (t + 1) * 128);
    // fence: no MFMA (or its lgkm wait) may be hoisted above this point, and
    // no ds_read/stage may sink below -> reads issue before compute.
    __builtin_amdgcn_sched_barrier(0);

    __builtin_amdgcn_s_setprio(1);
    #pragma unroll
    for (int h = 0; h < 2; ++h)
      #pragma unroll
      for (int d = 0; d < 3; ++d)
        #pragma unroll
        for (int mi = 0; mi < 4; ++mi)
          #pragma unroll
          for (int ni = 0; ni < 2; ++ni)
            acc[d][mi][ni] = __builtin_amdgcn_mfma_i32_16x16x64_i8(
                av[h][mi], bv[h][d][ni], acc[d][mi][ni], 0, 0, 0);
    __builtin_amdgcn_s_setprio(0);
    // pin: keep all MFMAs (and their lgkm waits) above the next barrier so no
    // ds_read of buf[cur] can still be outstanding when it gets overwritten.
    __builtin_amdgcn_sched_barrier(0);
    cur ^= 1;
  }

  // epilogue: recombine digits exactly in f64, leaky step, write mem_new,
  // and (fused) count spikes per row over this wave's 32-col half.
  const float* b1 = a.b1[g];
  const float* b2 = a.b2[g];
  const float* memg = a.mem[g];
  float* outg = a.out + (size_t)g * 4194304ull;
  double beta = fmin(fmax((double)(*a.beta[g]), 0.0), 1.0);
  double thr = (double)(*a.thr[g]);
  const float thrf = *a.thr[g];
  #pragma unroll
  for (int mi = 0; mi < 4; ++mi) {
    unsigned long long msk[2][4];
    #pragma unroll
    for (int ni = 0; ni < 2; ++ni) {
      int m0 = mt * 128 + wr * 64 + mi * 16 + ((l >> 4) << 2);
      int n  = nt * 64 + wc * 32 + ni * 16 + (l & 15);
      double bsum = (double)b1[n] + (double)b2[n];
      #pragma unroll
      for (int j = 0; j < 4; ++j) {
        double e = (double)acc[2][mi][ni][j] * 65536.0
                 + (double)acc[1][mi][ni][j] * 256.0
                 + (double)acc[0][mi][ni][j];
        double enc = e * (1.0 / 268435456.0) + bsum;
        size_t o = (size_t)(m0 + j) * 1024 + n;
        double mp = (double)memg[o];
        double reset = (mp - thr > 0.0) ? 1.0 : 0.0;
        double mn = beta * mp + enc - reset * thr;
        float v = (float)mn;
        outg[o] = v;
        msk[ni][j] = __ballot(v > thrf);   // bit l: col l&15, row-grp l>>4
      }
    }
    // lane r<16 stores the count for frag-row r = grp*4 + j over 32 cols
    int r = l & 15, grp = r >> 2, j = r & 3;
    unsigned c = (unsigned)__popcll((msk[0][j] >> (grp * 16)) & 0xFFFFull)
               + (unsigned)__popcll((msk[1][j] >> (grp * 16)) & 0xFFFFull);
    if (l < 16)
      a.cnt[((size_t)g * 4096 + mt * 128 + wr * 64 + mi * 16 + r) * 32
            + nt * 2 + wc] = c;
  }
}

// ---- finalize: counts -> f,i,g,o -> syn, mem_h, hidden (all f64) ------------
template <bool USE_WS>
__global__ __launch_bounds__(256) void k_fin(CArgs a) {
  const int b = blockIdx.x, tid = threadIdx.x;
  const int w = tid >> 6, l = tid & 63;
  __shared__ int scnt[4];
  __shared__ double sval[3];
  if (USE_WS) {
    __shared__ int part[128];
    if (tid < 128)
      part[tid] = (int)a.cnt[((size_t)(tid >> 5) * 4096 + b) * 32 + (tid & 31)];
    __syncthreads();
    if (tid < 4) {
      int s = 0;
      #pragma unroll
      for (int i = 0; i < 32; ++i) s += part[tid * 32 + i];
      scnt[tid] = s;
    }
    __syncthreads();
  } else {
    const float* mg = a.memo + (size_t)w * 4194304ull + (size_t)b * 1024;
    const float thrw = *a.thr[w];
    int cnt = 0;
    #pragma unroll
    for (int p = 0; p < 16; ++p) {
      float v = mg[l + p * 64];
      cnt += ((v - thrw) > 0.0f) ? 1 : 0;
    }
    #pragma unroll
    for (int off = 32; off; off >>= 1) cnt += __shfl_down(cnt, off, 64);
    if (l == 0) scnt[w] = cnt;
    __syncthreads();
  }
  if (tid == 0) {
    double mf = scnt[0] * (1.0 / 1024.0);
    double mi = scnt[1] * (1.0 / 1024.0);
    double mgv = scnt[2] * (1.0 / 1024.0);
    double mo = scnt[3] * (1.0 / 1024.0);
    double f  = 1.0 / (1.0 + exp(-mf));
    double ii = 1.0 / (1.0 + exp(-mi));
    double gv = tanh(mgv);
    double oo = 1.0 / (1.0 + exp(-mo));
    sval[0] = f; sval[1] = ii * gv; sval[2] = oo;
  }
  __syncthreads();
  const double f = sval[0], ig = sval[1], oo = sval[2];
  const double bh = fmin(fmax((double)(*a.beta_h), 0.0), 1.0);
  const double th = (double)(*a.thr_h);
  const size_t rb = (size_t)b * 2048;
  for (int j = tid; j < 2048; j += 256) {
    double s = f * (double)a.syn_prev[rb + j] + ig;
    double mp = (double)a.mem_hidden[rb + j];
    double reset = (mp - th > 0.0) ? 1.0 : 0.0;
    double mh = bh * mp + oo * tanh(s) - reset * th;
    a.syn[rb + j] = (float)s;
    a.memh[rb + j] = (float)mh;
    a.hid[rb + j] = ((mh - th) > 0.0) ? 1.0f : 0.0f;
  }
}

extern "C" void kernel_launch(void* const* d_in, const int* in_sizes, int n_in,
                              void* d_out, int out_size, void* d_ws, size_t ws_size,
                              hipStream_t stream) {
  (void)in_sizes; (void)n_in; (void)out_size;
  float* out = (float*)d_out;
  signed char* base8 = (signed char*)d_out;
  const bool use_ws = (d_ws != nullptr) && (ws_size >= CNT_BYTES);

  PrepArgs pr;
  for (int i = 0; i < 5; ++i) {
    pr.src[i] = (const int4*)d_in[i];
    pr.dst[i] = (int4*)(base8 + (i < 2 ? (AQ01_BYTE + (size_t)i * A_BYTES)
                                       : (AQ234_BYTE + (size_t)(i - 2) * A_BYTES)));
  }
  pr.Wq = base8;
  for (int g = 0; g < 4; ++g) {
    pr.W1[g] = (const float*)d_in[11 + 4 * g];
    pr.W2[g] = (const float*)d_in[13 + 4 * g];
  }
  GArgs ga;
  for (int g = 0; g < 4; ++g) {
    ga.ax[g]   = (const signed char*)pr.dst[g];
    ga.mem[g]  = (const float*)d_in[6 + g];
    ga.b1[g]   = (const float*)d_in[12 + 4 * g];
    ga.b2[g]   = (const float*)d_in[14 + 4 * g];
    ga.beta[g] = (const float*)d_in[27 + 2 * g];
    ga.thr[g]  = (const float*)d_in[28 + 2 * g];
  }
  ga.ah = (const signed char*)pr.dst[4];
  ga.Wq = base8;
  ga.out = out + OFF_MEM;
  ga.cnt = (unsigned int*)d_ws;

  CArgs ca;
  ca.memo = out + OFF_MEM;
  ca.syn_prev = (const float*)d_in[5];
  ca.mem_hidden = (const float*)d_in[10];
  for (int g = 0; g < 4; ++g) ca.thr[g] = (const float*)d_in[28 + 2 * g];
  ca.beta_h = (const float*)d_in[35];
  ca.thr_h = (const float*)d_in[36];
  ca.hid = out;
  ca.syn = out + OFF_SYN;
  ca.memh = out + OFF_MEMH;
  ca.cnt = (const unsigned int*)d_ws;

  k_prep<<<26624, 256, 0, stream>>>(pr);
  k_gemm<<<dim3(16, 32, 4), 256, 0, stream>>>(ga);
  if (use_ws) k_fin<true><<<4096, 256, 0, stream>>>(ca);
  else        k_fin<false><<<4096, 256, 0, stream>>>(ca);
}